// Round 1
// baseline (425.343 us; speedup 1.0000x reference)
//
#include <hip/hip_runtime.h>
#include <math.h>

#define BB 4
#define SS 4096
#define DD 2048
#define EE 64
#define KK 8
#define TT_TOTAL (BB*SS)      // 16384 tokens
#define TT 32                 // tokens per block
#define DK 32                 // D-chunk
#define E2 (2*EE)             // 128 stacked outputs (Wr rows then Wn rows)

__device__ __forceinline__ double softplus64(double x) {
    // logaddexp(x, 0) = max(x,0) + log1p(exp(-|x|))
    return fmax(x, 0.0) + log1p(exp(-fabs(x)));
}

__launch_bounds__(256, 2)
__global__ void router_kernel(const float* __restrict__ x,
                              const float* __restrict__ Wr,
                              const float* __restrict__ Wn,
                              const float* __restrict__ bias,
                              const float* __restrict__ noise_u,
                              float* __restrict__ out_probs,
                              float* __restrict__ out_idx)
{
    __shared__ double xs[TT][DK];     // 8 KB
    __shared__ double ws[DK][E2];     // 32 KB
    __shared__ double zbuf[TT][E2];   // 32 KB

    const int tid  = threadIdx.x;
    const int tok0 = blockIdx.x * TT;

    const int tg = tid >> 5;      // 0..7  -> tokens tg*4 .. tg*4+3
    const int eg = tid & 31;      // 0..31 -> outputs eg*4 .. eg*4+3

    double acc[4][4];
    #pragma unroll
    for (int j = 0; j < 4; ++j)
        #pragma unroll
        for (int i = 0; i < 4; ++i) acc[j][i] = 0.0;

    for (int c = 0; c < DD / DK; ++c) {
        const int k0 = c * DK;

        // stage x chunk: TT*DK = 1024 doubles, one float4 per thread
        {
            const int tok = tid >> 3;       // 0..31
            const int fi  = tid & 7;        // 0..7
            const float4 v = *reinterpret_cast<const float4*>(
                &x[(size_t)(tok0 + tok) * DD + k0 + fi * 4]);
            xs[tok][fi * 4 + 0] = (double)v.x;
            xs[tok][fi * 4 + 1] = (double)v.y;
            xs[tok][fi * 4 + 2] = (double)v.z;
            xs[tok][fi * 4 + 3] = (double)v.w;
        }
        // stage W chunk (Wr rows 0..63, Wn rows 64..127), transposed to [k][e2]
        #pragma unroll
        for (int it = 0; it < 4; ++it) {
            const int i  = tid + it * 256;  // 0..1023
            const int r  = i >> 3;          // 0..127
            const int fi = i & 7;           // 0..7
            const float* src = (r < EE) ? (Wr + (size_t)r * DD)
                                        : (Wn + (size_t)(r - EE) * DD);
            const float4 v = *reinterpret_cast<const float4*>(&src[k0 + fi * 4]);
            ws[fi * 4 + 0][r] = (double)v.x;
            ws[fi * 4 + 1][r] = (double)v.y;
            ws[fi * 4 + 2][r] = (double)v.z;
            ws[fi * 4 + 3][r] = (double)v.w;
        }
        __syncthreads();

        #pragma unroll 8
        for (int k = 0; k < DK; ++k) {
            double xv[4], wv[4];
            #pragma unroll
            for (int j = 0; j < 4; ++j) xv[j] = xs[tg * 4 + j][k];
            #pragma unroll
            for (int i = 0; i < 4; ++i) wv[i] = ws[k][eg * 4 + i];
            #pragma unroll
            for (int j = 0; j < 4; ++j)
                #pragma unroll
                for (int i = 0; i < 4; ++i)
                    acc[j][i] = fma(xv[j], wv[i], acc[j][i]);
        }
        __syncthreads();
    }

    // dump accumulators to LDS
    #pragma unroll
    for (int j = 0; j < 4; ++j)
        #pragma unroll
        for (int i = 0; i < 4; ++i)
            zbuf[tg * 4 + j][eg * 4 + i] = acc[j][i];
    __syncthreads();

    // phase 2: per-token noise + top-k + sparse softmax. 4 waves x 8 tokens.
    const int wid  = tid >> 6;    // 0..3
    const int lane = tid & 63;    // == expert id
    for (int tt = 0; tt < 8; ++tt) {
        const int tok = wid * 8 + tt;
        const size_t gtok = (size_t)tok0 + tok;

        const double logit = zbuf[tok][lane];
        const double noisy = zbuf[tok][EE + lane];
        const double z = (double)noise_u[gtok * EE + lane] * softplus64(noisy)
                         + logit + (double)bias[lane];

        double zw = z;
        bool   sel = false;
        double m0  = 0.0;
        #pragma unroll
        for (int it = 0; it < KK; ++it) {
            double v  = zw;
            int    ix = lane;
            #pragma unroll
            for (int off = 32; off > 0; off >>= 1) {
                const double ov = __shfl_xor(v, off, 64);
                const int    oi = __shfl_xor(ix, off, 64);
                if (ov > v || (ov == v && oi < ix)) { v = ov; ix = oi; }
            }
            if (it == 0) m0 = v;
            if (lane == ix) { sel = true; zw = -INFINITY; }
            if (lane == 0) out_idx[gtok * KK + it] = (float)ix;
        }

        const double ex = sel ? exp(z - m0) : 0.0;
        double den = ex;
        #pragma unroll
        for (int off = 32; off > 0; off >>= 1) den += __shfl_xor(den, off, 64);

        out_probs[gtok * EE + lane] = (float)(ex / den);
    }
}

__global__ void bias_kernel(const float* __restrict__ bias,
                            float* __restrict__ out_bias)
{
    const int e = threadIdx.x;
    if (e < EE) {
        // avg_load - total selections = 2048 - 131072 < 0  -> sign = -1 always
        const double load_violation = (double)(TT_TOTAL * KK) / EE
                                      - (double)(TT_TOTAL * KK);
        const double s = (load_violation > 0.0) ? 1.0
                         : ((load_violation < 0.0) ? -1.0 : 0.0);
        out_bias[e] = bias[e] + (float)(0.001 * s);
    }
}

extern "C" void kernel_launch(void* const* d_in, const int* in_sizes, int n_in,
                              void* d_out, int out_size, void* d_ws, size_t ws_size,
                              hipStream_t stream)
{
    const float* x       = (const float*)d_in[0];
    const float* Wr      = (const float*)d_in[1];
    const float* Wn      = (const float*)d_in[2];
    const float* bias    = (const float*)d_in[3];
    const float* noise_u = (const float*)d_in[4];

    float* out       = (float*)d_out;
    float* out_probs = out;                                        // T*E floats
    float* out_idx   = out + (size_t)TT_TOTAL * EE;                // T*K floats
    float* out_bias  = out + (size_t)TT_TOTAL * EE
                           + (size_t)TT_TOTAL * KK;                // E floats

    router_kernel<<<TT_TOTAL / TT, 256, 0, stream>>>(
        x, Wr, Wn, bias, noise_u, out_probs, out_idx);
    bias_kernel<<<1, 64, 0, stream>>>(bias, out_bias);
}

// Round 2
// 322.026 us; speedup vs baseline: 1.3208x; 1.3208x over previous
//
#include <hip/hip_runtime.h>
#include <math.h>

#define BB 4
#define SS 4096
#define DD 2048
#define EE 64
#define KK 8
#define TT_TOTAL (BB*SS)      // 16384 tokens
#define TT 32                 // tokens per block
#define DK 32                 // D-chunk
#define E2 (2*EE)             // 128 stacked outputs (Wr rows then Wn rows)
#define NC (DD/DK)            // 64 chunks
#define XROW (DK+1)           // padded row: 33 doubles -> 264B stride, 2-way banks
#define ZROW (E2+1)           // 129

#define SMEM_PHASE1 ((TT*XROW + E2*XROW)*8)   // 8448 + 33792 = 42240 B
#define SMEM_PHASE2 (TT*ZROW*8)               // 33024 B
#define SMEM_BYTES  (SMEM_PHASE1 > SMEM_PHASE2 ? SMEM_PHASE1 : SMEM_PHASE2)

__device__ __forceinline__ double softplus64(double x) {
    // logaddexp(x, 0) = max(x,0) + log1p(exp(-|x|))
    return fmax(x, 0.0) + log1p(exp(-fabs(x)));
}

__launch_bounds__(256, 2)
__global__ void router_kernel(const float* __restrict__ x,
                              const float* __restrict__ Wr,
                              const float* __restrict__ Wn,
                              const float* __restrict__ bias,
                              const float* __restrict__ noise_u,
                              float* __restrict__ out_probs,
                              float* __restrict__ out_idx)
{
    __shared__ __align__(16) char smem_raw[SMEM_BYTES];
    double (*xs)[XROW]  = reinterpret_cast<double(*)[XROW]>(smem_raw);              // [TT][33]
    double (*ws)[XROW]  = reinterpret_cast<double(*)[XROW]>(smem_raw + TT*XROW*8);  // [E2][33], row-major like global W
    double (*zbuf)[ZROW]= reinterpret_cast<double(*)[ZROW]>(smem_raw);              // [TT][129], aliases phase-1 bufs

    const int tid  = threadIdx.x;
    const int tok0 = blockIdx.x * TT;
    const int tg   = tid >> 5;      // 0..7  -> tokens tg*4 .. tg*4+3
    const int eg   = tid & 31;      // 0..31 -> experts eg, eg+32, eg+64, eg+96

    // staging mapping: thread -> (row, float4-slot)
    const int stok = tid >> 3;      // 0..31 (x row / W row base)
    const int sfi  = tid & 7;       // 0..7  (float4 slot within 32-wide chunk)

    const float* xsrc = x + (size_t)(tok0 + stok) * DD + sfi * 4;
    const float* wsrc[4];
    #pragma unroll
    for (int it = 0; it < 4; ++it) {
        const int r = it * 32 + stok;   // 0..127
        wsrc[it] = ((r < EE) ? (Wr + (size_t)r * DD)
                             : (Wn + (size_t)(r - EE) * DD)) + sfi * 4;
    }

    double acc[4][4];
    #pragma unroll
    for (int j = 0; j < 4; ++j)
        #pragma unroll
        for (int i = 0; i < 4; ++i) acc[j][i] = 0.0;

    // software pipeline: preload chunk 0
    float4 xr  = *reinterpret_cast<const float4*>(xsrc);
    float4 wr0 = *reinterpret_cast<const float4*>(wsrc[0]);
    float4 wr1 = *reinterpret_cast<const float4*>(wsrc[1]);
    float4 wr2 = *reinterpret_cast<const float4*>(wsrc[2]);
    float4 wr3 = *reinterpret_cast<const float4*>(wsrc[3]);

    for (int c = 0; c < NC; ++c) {
        __syncthreads();   // previous chunk's compute done -> LDS writable

        // stage regs -> LDS (f32 -> f64 exact). 2-way bank pattern = free.
        {
            const int col = sfi * 4;
            xs[stok][col+0] = (double)xr.x;
            xs[stok][col+1] = (double)xr.y;
            xs[stok][col+2] = (double)xr.z;
            xs[stok][col+3] = (double)xr.w;
            ws[stok      ][col+0] = (double)wr0.x;
            ws[stok      ][col+1] = (double)wr0.y;
            ws[stok      ][col+2] = (double)wr0.z;
            ws[stok      ][col+3] = (double)wr0.w;
            ws[stok + 32 ][col+0] = (double)wr1.x;
            ws[stok + 32 ][col+1] = (double)wr1.y;
            ws[stok + 32 ][col+2] = (double)wr1.z;
            ws[stok + 32 ][col+3] = (double)wr1.w;
            ws[stok + 64 ][col+0] = (double)wr2.x;
            ws[stok + 64 ][col+1] = (double)wr2.y;
            ws[stok + 64 ][col+2] = (double)wr2.z;
            ws[stok + 64 ][col+3] = (double)wr2.w;
            ws[stok + 96 ][col+0] = (double)wr3.x;
            ws[stok + 96 ][col+1] = (double)wr3.y;
            ws[stok + 96 ][col+2] = (double)wr3.z;
            ws[stok + 96 ][col+3] = (double)wr3.w;
        }
        __syncthreads();

        // issue next chunk's global loads; they land during this chunk's compute
        if (c + 1 < NC) {
            const int off = (c + 1) * DK;
            xr  = *reinterpret_cast<const float4*>(xsrc + off);
            wr0 = *reinterpret_cast<const float4*>(wsrc[0] + off);
            wr1 = *reinterpret_cast<const float4*>(wsrc[1] + off);
            wr2 = *reinterpret_cast<const float4*>(wsrc[2] + off);
            wr3 = *reinterpret_cast<const float4*>(wsrc[3] + off);
        }

        // compute: xv reads broadcast (free), wv reads stride-264B (2-way, free)
        #pragma unroll 4
        for (int k = 0; k < DK; ++k) {
            double xv[4], wv[4];
            #pragma unroll
            for (int j = 0; j < 4; ++j) xv[j] = xs[tg * 4 + j][k];
            #pragma unroll
            for (int i = 0; i < 4; ++i) wv[i] = ws[eg + 32 * i][k];
            #pragma unroll
            for (int j = 0; j < 4; ++j)
                #pragma unroll
                for (int i = 0; i < 4; ++i)
                    acc[j][i] = fma(xv[j], wv[i], acc[j][i]);
        }
    }

    __syncthreads();   // all reads of xs/ws done before zbuf alias-write
    #pragma unroll
    for (int j = 0; j < 4; ++j)
        #pragma unroll
        for (int i = 0; i < 4; ++i)
            zbuf[tg * 4 + j][eg + 32 * i] = acc[j][i];
    __syncthreads();

    // phase 2: per-token noise + top-k + sparse softmax. 4 waves x 8 tokens.
    const int wid  = tid >> 6;    // 0..3
    const int lane = tid & 63;    // == expert id
    for (int tt = 0; tt < 8; ++tt) {
        const int tok = wid * 8 + tt;
        const size_t gtok = (size_t)tok0 + tok;

        const double logit = zbuf[tok][lane];
        const double noisy = zbuf[tok][EE + lane];
        const double z = (double)noise_u[gtok * EE + lane] * softplus64(noisy)
                         + logit + (double)bias[lane];

        double zw = z;
        bool   sel = false;
        double m0  = 0.0;
        #pragma unroll
        for (int it = 0; it < KK; ++it) {
            double v  = zw;
            int    ix = lane;
            #pragma unroll
            for (int off = 32; off > 0; off >>= 1) {
                const double ov = __shfl_xor(v, off, 64);
                const int    oi = __shfl_xor(ix, off, 64);
                if (ov > v || (ov == v && oi < ix)) { v = ov; ix = oi; }
            }
            if (it == 0) m0 = v;
            if (lane == ix) { sel = true; zw = -INFINITY; }
            if (lane == 0) out_idx[gtok * KK + it] = (float)ix;
        }

        const double ex = sel ? exp(z - m0) : 0.0;
        double den = ex;
        #pragma unroll
        for (int off = 32; off > 0; off >>= 1) den += __shfl_xor(den, off, 64);

        out_probs[gtok * EE + lane] = (float)(ex / den);
    }
}

__global__ void bias_kernel(const float* __restrict__ bias,
                            float* __restrict__ out_bias)
{
    const int e = threadIdx.x;
    if (e < EE) {
        // avg_load - total selections = 2048 - 131072 < 0 -> sign = -1 always
        const double load_violation = (double)(TT_TOTAL * KK) / EE
                                      - (double)(TT_TOTAL * KK);
        const double s = (load_violation > 0.0) ? 1.0
                         : ((load_violation < 0.0) ? -1.0 : 0.0);
        out_bias[e] = bias[e] + (float)(0.001 * s);
    }
}

extern "C" void kernel_launch(void* const* d_in, const int* in_sizes, int n_in,
                              void* d_out, int out_size, void* d_ws, size_t ws_size,
                              hipStream_t stream)
{
    const float* x       = (const float*)d_in[0];
    const float* Wr      = (const float*)d_in[1];
    const float* Wn      = (const float*)d_in[2];
    const float* bias    = (const float*)d_in[3];
    const float* noise_u = (const float*)d_in[4];

    float* out       = (float*)d_out;
    float* out_probs = out;                                        // T*E floats
    float* out_idx   = out + (size_t)TT_TOTAL * EE;                // T*K floats
    float* out_bias  = out + (size_t)TT_TOTAL * EE
                           + (size_t)TT_TOTAL * KK;                // E floats

    router_kernel<<<TT_TOTAL / TT, 256, 0, stream>>>(
        x, Wr, Wn, bias, noise_u, out_probs, out_idx);
    bias_kernel<<<1, 64, 0, stream>>>(bias, out_bias);
}

// Round 4
// 302.002 us; speedup vs baseline: 1.4084x; 1.0663x over previous
//
#include <hip/hip_runtime.h>
#include <math.h>

#define BB 4
#define SS 4096
#define DD 2048
#define EE 64
#define KK 8
#define TT_TOTAL (BB*SS)      // 16384 tokens
#define TT 32                 // tokens per block
#define DK 32                 // D-chunk
#define E2 128                // stacked outputs (Wr rows 0..63, Wn rows 64..127)
#define NC (DD/DK)            // 64 chunks
#define XT 34                 // xs row = 32 tokens + 2 pad (272 B, 16B-aligned rows)
#define WR 130                // wt row = 128 experts + 2 pad (1040 B, 16B-aligned rows)
#define ZR 130                // zbuf row (1040 B, 16B-aligned rows)

#define SMEM_BYTES ((DK*XT + DK*WR)*8)   // 8704 + 33280 = 41984 B

typedef double double2_t __attribute__((ext_vector_type(2)));

__device__ __forceinline__ double softplus64(double x) {
    return fmax(x, 0.0) + log1p(exp(-fabs(x)));
}

__launch_bounds__(256, 3)
__global__ void router_kernel(const float* __restrict__ x,
                              const float* __restrict__ Wr,
                              const float* __restrict__ Wn,
                              const float* __restrict__ bias,
                              const float* __restrict__ noise_u,
                              float* __restrict__ out_probs,
                              float* __restrict__ out_idx)
{
    __shared__ __align__(16) char smem_raw[SMEM_BYTES];
    double (*xs)[XT] = reinterpret_cast<double(*)[XT]>(smem_raw);             // xs[k][tok]
    double (*wt)[WR] = reinterpret_cast<double(*)[WR]>(smem_raw + DK*XT*8);   // wt[k][e]
    double (*zbuf)[ZR] = reinterpret_cast<double(*)[ZR]>(smem_raw);           // [TT][130] alias

    const int tid  = threadIdx.x;
    const int tok0 = blockIdx.x * TT;

    // ---- staging mapping (R2-verified): thread -> (row, float4 slot) ----
    const int stok = tid >> 3;      // 0..31
    const int sfi  = tid & 7;       // 0..7
    const float* xsrc = x + (size_t)(tok0 + stok) * DD + sfi * 4;
    const float* wsrc[4];
    #pragma unroll
    for (int it = 0; it < 4; ++it) {
        const int r = it * 32 + stok;   // 0..127
        wsrc[it] = ((r < EE) ? (Wr + (size_t)r * DD)
                             : (Wn + (size_t)(r - EE) * DD)) + sfi * 4;
    }

    // ---- compute mapping: 4 tokens x 4 experts per thread ----
    const int tg = tid >> 5;        // 0..7 -> tokens tg*4 .. tg*4+3
    const int eg = tid & 31;        // 0..31 -> experts {2eg, 2eg+1, 64+2eg, 64+2eg+1}

    double acc[4][4];
    #pragma unroll
    for (int t = 0; t < 4; ++t)
        #pragma unroll
        for (int i = 0; i < 4; ++i) acc[t][i] = 0.0;

    // software pipeline: preload chunk 0
    float4 xr  = *reinterpret_cast<const float4*>(xsrc);
    float4 wr0 = *reinterpret_cast<const float4*>(wsrc[0]);
    float4 wr1 = *reinterpret_cast<const float4*>(wsrc[1]);
    float4 wr2 = *reinterpret_cast<const float4*>(wsrc[2]);
    float4 wr3 = *reinterpret_cast<const float4*>(wsrc[3]);

    for (int c = 0; c < NC; ++c) {
        __syncthreads();   // previous chunk's reads done -> LDS writable

        // stage regs -> LDS, transposed (f32 -> f64 exact)
        {
            const int k0 = sfi * 4;
            xs[k0+0][stok] = (double)xr.x;
            xs[k0+1][stok] = (double)xr.y;
            xs[k0+2][stok] = (double)xr.z;
            xs[k0+3][stok] = (double)xr.w;
            wt[k0+0][stok      ] = (double)wr0.x;
            wt[k0+1][stok      ] = (double)wr0.y;
            wt[k0+2][stok      ] = (double)wr0.z;
            wt[k0+3][stok      ] = (double)wr0.w;
            wt[k0+0][stok + 32 ] = (double)wr1.x;
            wt[k0+1][stok + 32 ] = (double)wr1.y;
            wt[k0+2][stok + 32 ] = (double)wr1.z;
            wt[k0+3][stok + 32 ] = (double)wr1.w;
            wt[k0+0][stok + 64 ] = (double)wr2.x;
            wt[k0+1][stok + 64 ] = (double)wr2.y;
            wt[k0+2][stok + 64 ] = (double)wr2.z;
            wt[k0+3][stok + 64 ] = (double)wr2.w;
            wt[k0+0][stok + 96 ] = (double)wr3.x;
            wt[k0+1][stok + 96 ] = (double)wr3.y;
            wt[k0+2][stok + 96 ] = (double)wr3.z;
            wt[k0+3][stok + 96 ] = (double)wr3.w;
        }
        __syncthreads();

        // issue next chunk's global loads; they land during this chunk's compute
        if (c + 1 < NC) {
            const int off = (c + 1) * DK;
            xr  = *reinterpret_cast<const float4*>(xsrc + off);
            wr0 = *reinterpret_cast<const float4*>(wsrc[0] + off);
            wr1 = *reinterpret_cast<const float4*>(wsrc[1] + off);
            wr2 = *reinterpret_cast<const float4*>(wsrc[2] + off);
            wr3 = *reinterpret_cast<const float4*>(wsrc[3] + off);
        }

        // compute: per k, 4x ds_read_b128 (conflict-free, aligned) + 16 f64 FMA
        #pragma unroll 4
        for (int k = 0; k < DK; ++k) {
            const double2_t xv0 = *reinterpret_cast<const double2_t*>(&xs[k][tg * 4]);
            const double2_t xv1 = *reinterpret_cast<const double2_t*>(&xs[k][tg * 4 + 2]);
            const double2_t w0  = *reinterpret_cast<const double2_t*>(&wt[k][2 * eg]);
            const double2_t w1  = *reinterpret_cast<const double2_t*>(&wt[k][64 + 2 * eg]);
            const double xvv[4] = {xv0.x, xv0.y, xv1.x, xv1.y};
            #pragma unroll
            for (int t = 0; t < 4; ++t) {
                acc[t][0] = fma(xvv[t], w0.x, acc[t][0]);
                acc[t][1] = fma(xvv[t], w0.y, acc[t][1]);
                acc[t][2] = fma(xvv[t], w1.x, acc[t][2]);
                acc[t][3] = fma(xvv[t], w1.y, acc[t][3]);
            }
        }
    }

    __syncthreads();   // all xs/wt reads done before zbuf alias-write
    #pragma unroll
    for (int t = 0; t < 4; ++t) {
        double2_t lo = {acc[t][0], acc[t][1]};
        double2_t hi = {acc[t][2], acc[t][3]};
        *reinterpret_cast<double2_t*>(&zbuf[tg * 4 + t][2 * eg])      = lo;
        *reinterpret_cast<double2_t*>(&zbuf[tg * 4 + t][64 + 2 * eg]) = hi;
    }
    __syncthreads();

    // phase 2: per-token noise + top-k + sparse softmax. 4 waves x 8 tokens.
    const int wid  = tid >> 6;    // 0..3
    const int lane = tid & 63;    // == expert id
    for (int tt = 0; tt < 8; ++tt) {
        const int tok = wid * 8 + tt;
        const size_t gtok = (size_t)tok0 + tok;

        const double logit = zbuf[tok][lane];
        const double noisy = zbuf[tok][EE + lane];
        const double z = (double)noise_u[gtok * EE + lane] * softplus64(noisy)
                         + logit + (double)bias[lane];

        double zw = z;
        bool   sel = false;
        double m0  = 0.0;
        #pragma unroll
        for (int it = 0; it < KK; ++it) {
            double v  = zw;
            int    ix = lane;
            #pragma unroll
            for (int off = 32; off > 0; off >>= 1) {
                const double ov = __shfl_xor(v, off, 64);
                const int    oi = __shfl_xor(ix, off, 64);
                if (ov > v || (ov == v && oi < ix)) { v = ov; ix = oi; }
            }
            if (it == 0) m0 = v;
            if (lane == ix) { sel = true; zw = -INFINITY; }
            if (lane == 0) out_idx[gtok * KK + it] = (float)ix;
        }

        const double ex = sel ? exp(z - m0) : 0.0;
        double den = ex;
        #pragma unroll
        for (int off = 32; off > 0; off >>= 1) den += __shfl_xor(den, off, 64);

        out_probs[gtok * EE + lane] = (float)(ex / den);
    }
}

__global__ void bias_kernel(const float* __restrict__ bias,
                            float* __restrict__ out_bias)
{
    const int e = threadIdx.x;
    if (e < EE) {
        // avg_load - total selections = 2048 - 131072 < 0 -> sign = -1 always
        const double load_violation = (double)(TT_TOTAL * KK) / EE
                                      - (double)(TT_TOTAL * KK);
        const double s = (load_violation > 0.0) ? 1.0
                         : ((load_violation < 0.0) ? -1.0 : 0.0);
        out_bias[e] = bias[e] + (float)(0.001 * s);
    }
}

extern "C" void kernel_launch(void* const* d_in, const int* in_sizes, int n_in,
                              void* d_out, int out_size, void* d_ws, size_t ws_size,
                              hipStream_t stream)
{
    const float* x       = (const float*)d_in[0];
    const float* Wr      = (const float*)d_in[1];
    const float* Wn      = (const float*)d_in[2];
    const float* bias    = (const float*)d_in[3];
    const float* noise_u = (const float*)d_in[4];

    float* out       = (float*)d_out;
    float* out_probs = out;                                        // T*E floats
    float* out_idx   = out + (size_t)TT_TOTAL * EE;                // T*K floats
    float* out_bias  = out + (size_t)TT_TOTAL * EE
                           + (size_t)TT_TOTAL * KK;                // E floats

    router_kernel<<<TT_TOTAL / TT, 256, 0, stream>>>(
        x, Wr, Wn, bias, noise_u, out_probs, out_idx);
    bias_kernel<<<1, 64, 0, stream>>>(bias, out_bias);
}

// Round 5
// 301.975 us; speedup vs baseline: 1.4085x; 1.0001x over previous
//
#include <hip/hip_runtime.h>
#include <math.h>

#define BB 4
#define SS 4096
#define DD 2048
#define EE 64
#define KK 8
#define TT_TOTAL (BB*SS)      // 16384 tokens
#define E2 128                // stacked outputs (Wr 0..63, Wn 64..127)

// ---------- kernel 1 (GEMM) tiling ----------
#define BT 32                 // tokens per block
#define BE 64                 // outputs per block
#define DK 32                 // D-chunk
#define NC (DD/DK)            // 64 chunks
#define XT 34                 // xs row doubles (272 B, 16B-aligned rows)
#define WT 66                 // ws row doubles (528 B, 16B-aligned rows)

typedef double double2_t __attribute__((ext_vector_type(2)));
typedef double double4_t __attribute__((ext_vector_type(4)));

__device__ __forceinline__ double softplus64(double x) {
    return fmax(x, 0.0) + log1p(exp(-fabs(x)));
}

// =====================================================================
// Kernel 1: z[tok][out] = sum_k x[tok][k] * W[out][k]  (f64, ascending k)
// grid.x = 1024: bt = bid>>1 (token block), be = bid&1 (output half)
// =====================================================================
__launch_bounds__(256, 4)
__global__ void gemm_kernel(const float* __restrict__ x,
                            const float* __restrict__ Wr,
                            const float* __restrict__ Wn,
                            double* __restrict__ zout)
{
    __shared__ __align__(16) double xs[DK][XT];   // xs[k][tok]  8704 B
    __shared__ __align__(16) double ws[DK][WT];   // ws[k][out] 16896 B

    const int tid  = threadIdx.x;
    const int bt   = blockIdx.x >> 1;
    const int be   = blockIdx.x & 1;
    const int tok0 = bt * BT;
    const int e0   = be * BE;

    // ---- staging mapping: thread -> (k within chunk, 4-col group) ----
    const int kk = tid & 31;
    const int tq = tid >> 5;              // 0..7
    const float* xsrc[4];
    const float* wsrc[8];
    #pragma unroll
    for (int j = 0; j < 4; ++j)
        xsrc[j] = x + (size_t)(tok0 + 4 * tq + j) * DD + kk;
    #pragma unroll
    for (int j = 0; j < 4; ++j) {
        const int e  = e0 + 4 * tq + j;        // cols 0..31 of this half
        const int e2 = e0 + 32 + 4 * tq + j;   // cols 32..63
        wsrc[j]     = ((e  < EE) ? Wr + (size_t)e * DD
                                 : Wn + (size_t)(e  - EE) * DD) + kk;
        wsrc[4 + j] = ((e2 < EE) ? Wr + (size_t)e2 * DD
                                 : Wn + (size_t)(e2 - EE) * DD) + kk;
    }

    // ---- compute mapping: 2 tokens x 4 outputs per thread ----
    const int og = tid & 15;              // outs {2og,2og+1, 32+2og,32+2og+1}
    const int tp = tid >> 4;              // toks {2tp, 2tp+1}

    double acc[2][4];
    #pragma unroll
    for (int t = 0; t < 2; ++t)
        #pragma unroll
        for (int i = 0; i < 4; ++i) acc[t][i] = 0.0;

    // software pipeline: preload chunk 0
    float xr[4], wr[8];
    #pragma unroll
    for (int j = 0; j < 4; ++j) xr[j] = xsrc[j][0];
    #pragma unroll
    for (int j = 0; j < 8; ++j) wr[j] = wsrc[j][0];

    for (int c = 0; c < NC; ++c) {
        __syncthreads();   // previous chunk's reads done -> LDS writable

        // contiguous b128 writes, uniform bank spread (no scatter conflicts)
        {
            double4_t xv = {(double)xr[0], (double)xr[1], (double)xr[2], (double)xr[3]};
            *reinterpret_cast<double4_t*>(&xs[kk][4 * tq]) = xv;
            double4_t w0 = {(double)wr[0], (double)wr[1], (double)wr[2], (double)wr[3]};
            *reinterpret_cast<double4_t*>(&ws[kk][4 * tq]) = w0;
            double4_t w1 = {(double)wr[4], (double)wr[5], (double)wr[6], (double)wr[7]};
            *reinterpret_cast<double4_t*>(&ws[kk][32 + 4 * tq]) = w1;
        }
        __syncthreads();

        // issue next chunk's global loads; land during this chunk's compute
        if (c + 1 < NC) {
            const int off = (c + 1) * DK;
            #pragma unroll
            for (int j = 0; j < 4; ++j) xr[j] = xsrc[j][off];
            #pragma unroll
            for (int j = 0; j < 8; ++j) wr[j] = wsrc[j][off];
        }

        // per k: 3x ds_read_b128 (broadcast-merged, full bank coverage) + 8 f64 FMA
        #pragma unroll 4
        for (int k = 0; k < DK; ++k) {
            const double2_t xv = *reinterpret_cast<const double2_t*>(&xs[k][2 * tp]);
            const double2_t w0 = *reinterpret_cast<const double2_t*>(&ws[k][2 * og]);
            const double2_t w1 = *reinterpret_cast<const double2_t*>(&ws[k][32 + 2 * og]);
            acc[0][0] = fma(xv.x, w0.x, acc[0][0]);
            acc[0][1] = fma(xv.x, w0.y, acc[0][1]);
            acc[0][2] = fma(xv.x, w1.x, acc[0][2]);
            acc[0][3] = fma(xv.x, w1.y, acc[0][3]);
            acc[1][0] = fma(xv.y, w0.x, acc[1][0]);
            acc[1][1] = fma(xv.y, w0.y, acc[1][1]);
            acc[1][2] = fma(xv.y, w1.x, acc[1][2]);
            acc[1][3] = fma(xv.y, w1.y, acc[1][3]);
        }
    }

    // write z: per token two 16B stores (outs 2og,2og+1 and 32+2og,32+2og+1)
    #pragma unroll
    for (int t = 0; t < 2; ++t) {
        const size_t base = (size_t)(tok0 + 2 * tp + t) * E2 + e0;
        double2_t lo = {acc[t][0], acc[t][1]};
        double2_t hi = {acc[t][2], acc[t][3]};
        *reinterpret_cast<double2_t*>(&zout[base + 2 * og])      = lo;
        *reinterpret_cast<double2_t*>(&zout[base + 32 + 2 * og]) = hi;
    }
}

// =====================================================================
// Kernel 2: noise + top-k + sparse softmax (verbatim R4 phase-2 math)
// =====================================================================
__launch_bounds__(256, 4)
__global__ void topk_kernel(const double* __restrict__ z,
                            const float* __restrict__ bias,
                            const float* __restrict__ noise_u,
                            float* __restrict__ out_probs,
                            float* __restrict__ out_idx)
{
    const int tid  = threadIdx.x;
    const int wid  = tid >> 6;    // 0..3
    const int lane = tid & 63;    // == expert id
    const int tok0 = blockIdx.x * 32;

    for (int tt = 0; tt < 8; ++tt) {
        const int tok = tok0 + wid * 8 + tt;
        const size_t gtok = (size_t)tok;

        const double logit = z[(size_t)tok * E2 + lane];
        const double noisy = z[(size_t)tok * E2 + EE + lane];
        const double zv = (double)noise_u[gtok * EE + lane] * softplus64(noisy)
                          + logit + (double)bias[lane];

        double zw = zv;
        bool   sel = false;
        double m0  = 0.0;
        #pragma unroll
        for (int it = 0; it < KK; ++it) {
            double v  = zw;
            int    ix = lane;
            #pragma unroll
            for (int off = 32; off > 0; off >>= 1) {
                const double ov = __shfl_xor(v, off, 64);
                const int    oi = __shfl_xor(ix, off, 64);
                if (ov > v || (ov == v && oi < ix)) { v = ov; ix = oi; }
            }
            if (it == 0) m0 = v;
            if (lane == ix) { sel = true; zw = -INFINITY; }
            if (lane == 0) out_idx[gtok * KK + it] = (float)ix;
        }

        const double ex = sel ? exp(zv - m0) : 0.0;
        double den = ex;
        #pragma unroll
        for (int off = 32; off > 0; off >>= 1) den += __shfl_xor(den, off, 64);

        out_probs[gtok * EE + lane] = (float)(ex / den);
    }
}

// =====================================================================
// Fallback: R4 monolithic kernel (verified) if ws too small
// =====================================================================
#define F_TT 32
#define F_XT 34
#define F_WR 130
#define F_ZR 130
#define F_SMEM ((DK*F_XT + DK*F_WR)*8)

__launch_bounds__(256, 3)
__global__ void router_kernel(const float* __restrict__ x,
                              const float* __restrict__ Wr,
                              const float* __restrict__ Wn,
                              const float* __restrict__ bias,
                              const float* __restrict__ noise_u,
                              float* __restrict__ out_probs,
                              float* __restrict__ out_idx)
{
    __shared__ __align__(16) char smem_raw[F_SMEM];
    double (*xs)[F_XT] = reinterpret_cast<double(*)[F_XT]>(smem_raw);
    double (*wt)[F_WR] = reinterpret_cast<double(*)[F_WR]>(smem_raw + DK*F_XT*8);
    double (*zbuf)[F_ZR] = reinterpret_cast<double(*)[F_ZR]>(smem_raw);

    const int tid  = threadIdx.x;
    const int tok0 = blockIdx.x * F_TT;
    const int stok = tid >> 3;
    const int sfi  = tid & 7;
    const float* xsrc = x + (size_t)(tok0 + stok) * DD + sfi * 4;
    const float* wsrc[4];
    #pragma unroll
    for (int it = 0; it < 4; ++it) {
        const int r = it * 32 + stok;
        wsrc[it] = ((r < EE) ? (Wr + (size_t)r * DD)
                             : (Wn + (size_t)(r - EE) * DD)) + sfi * 4;
    }
    const int tg = tid >> 5;
    const int eg = tid & 31;

    double acc[4][4];
    #pragma unroll
    for (int t = 0; t < 4; ++t)
        #pragma unroll
        for (int i = 0; i < 4; ++i) acc[t][i] = 0.0;

    float4 xr  = *reinterpret_cast<const float4*>(xsrc);
    float4 wr0 = *reinterpret_cast<const float4*>(wsrc[0]);
    float4 wr1 = *reinterpret_cast<const float4*>(wsrc[1]);
    float4 wr2 = *reinterpret_cast<const float4*>(wsrc[2]);
    float4 wr3 = *reinterpret_cast<const float4*>(wsrc[3]);

    for (int c = 0; c < NC; ++c) {
        __syncthreads();
        {
            const int k0 = sfi * 4;
            xs[k0+0][stok] = (double)xr.x;  xs[k0+1][stok] = (double)xr.y;
            xs[k0+2][stok] = (double)xr.z;  xs[k0+3][stok] = (double)xr.w;
            wt[k0+0][stok      ] = (double)wr0.x; wt[k0+1][stok      ] = (double)wr0.y;
            wt[k0+2][stok      ] = (double)wr0.z; wt[k0+3][stok      ] = (double)wr0.w;
            wt[k0+0][stok + 32 ] = (double)wr1.x; wt[k0+1][stok + 32 ] = (double)wr1.y;
            wt[k0+2][stok + 32 ] = (double)wr1.z; wt[k0+3][stok + 32 ] = (double)wr1.w;
            wt[k0+0][stok + 64 ] = (double)wr2.x; wt[k0+1][stok + 64 ] = (double)wr2.y;
            wt[k0+2][stok + 64 ] = (double)wr2.z; wt[k0+3][stok + 64 ] = (double)wr2.w;
            wt[k0+0][stok + 96 ] = (double)wr3.x; wt[k0+1][stok + 96 ] = (double)wr3.y;
            wt[k0+2][stok + 96 ] = (double)wr3.z; wt[k0+3][stok + 96 ] = (double)wr3.w;
        }
        __syncthreads();
        if (c + 1 < NC) {
            const int off = (c + 1) * DK;
            xr  = *reinterpret_cast<const float4*>(xsrc + off);
            wr0 = *reinterpret_cast<const float4*>(wsrc[0] + off);
            wr1 = *reinterpret_cast<const float4*>(wsrc[1] + off);
            wr2 = *reinterpret_cast<const float4*>(wsrc[2] + off);
            wr3 = *reinterpret_cast<const float4*>(wsrc[3] + off);
        }
        #pragma unroll 4
        for (int k = 0; k < DK; ++k) {
            const double2_t xv0 = *reinterpret_cast<const double2_t*>(&xs[k][tg * 4]);
            const double2_t xv1 = *reinterpret_cast<const double2_t*>(&xs[k][tg * 4 + 2]);
            const double2_t w0  = *reinterpret_cast<const double2_t*>(&wt[k][2 * eg]);
            const double2_t w1  = *reinterpret_cast<const double2_t*>(&wt[k][64 + 2 * eg]);
            const double xvv[4] = {xv0.x, xv0.y, xv1.x, xv1.y};
            #pragma unroll
            for (int t = 0; t < 4; ++t) {
                acc[t][0] = fma(xvv[t], w0.x, acc[t][0]);
                acc[t][1] = fma(xvv[t], w0.y, acc[t][1]);
                acc[t][2] = fma(xvv[t], w1.x, acc[t][2]);
                acc[t][3] = fma(xvv[t], w1.y, acc[t][3]);
            }
        }
    }
    __syncthreads();
    #pragma unroll
    for (int t = 0; t < 4; ++t) {
        double2_t lo = {acc[t][0], acc[t][1]};
        double2_t hi = {acc[t][2], acc[t][3]};
        *reinterpret_cast<double2_t*>(&zbuf[tg * 4 + t][2 * eg])      = lo;
        *reinterpret_cast<double2_t*>(&zbuf[tg * 4 + t][64 + 2 * eg]) = hi;
    }
    __syncthreads();

    const int wid  = tid >> 6;
    const int lane = tid & 63;
    for (int tt = 0; tt < 8; ++tt) {
        const int tok = wid * 8 + tt;
        const size_t gtok = (size_t)tok0 + tok;
        const double logit = zbuf[tok][lane];
        const double noisy = zbuf[tok][EE + lane];
        const double zv = (double)noise_u[gtok * EE + lane] * softplus64(noisy)
                          + logit + (double)bias[lane];
        double zw = zv;
        bool   sel = false;
        double m0  = 0.0;
        #pragma unroll
        for (int it = 0; it < KK; ++it) {
            double v  = zw;
            int    ix = lane;
            #pragma unroll
            for (int off = 32; off > 0; off >>= 1) {
                const double ov = __shfl_xor(v, off, 64);
                const int    oi = __shfl_xor(ix, off, 64);
                if (ov > v || (ov == v && oi < ix)) { v = ov; ix = oi; }
            }
            if (it == 0) m0 = v;
            if (lane == ix) { sel = true; zw = -INFINITY; }
            if (lane == 0) out_idx[gtok * KK + it] = (float)ix;
        }
        const double ex = sel ? exp(zv - m0) : 0.0;
        double den = ex;
        #pragma unroll
        for (int off = 32; off > 0; off >>= 1) den += __shfl_xor(den, off, 64);
        out_probs[gtok * EE + lane] = (float)(ex / den);
    }
}

__global__ void bias_kernel(const float* __restrict__ bias,
                            float* __restrict__ out_bias)
{
    const int e = threadIdx.x;
    if (e < EE) {
        const double load_violation = (double)(TT_TOTAL * KK) / EE
                                      - (double)(TT_TOTAL * KK);
        const double s = (load_violation > 0.0) ? 1.0
                         : ((load_violation < 0.0) ? -1.0 : 0.0);
        out_bias[e] = bias[e] + (float)(0.001 * s);
    }
}

extern "C" void kernel_launch(void* const* d_in, const int* in_sizes, int n_in,
                              void* d_out, int out_size, void* d_ws, size_t ws_size,
                              hipStream_t stream)
{
    const float* x       = (const float*)d_in[0];
    const float* Wr      = (const float*)d_in[1];
    const float* Wn      = (const float*)d_in[2];
    const float* bias    = (const float*)d_in[3];
    const float* noise_u = (const float*)d_in[4];

    float* out       = (float*)d_out;
    float* out_probs = out;
    float* out_idx   = out + (size_t)TT_TOTAL * EE;
    float* out_bias  = out + (size_t)TT_TOTAL * EE + (size_t)TT_TOTAL * KK;

    const size_t z_bytes = (size_t)TT_TOTAL * E2 * sizeof(double);

    if (ws_size >= z_bytes) {
        double* z = (double*)d_ws;
        gemm_kernel<<<(TT_TOTAL / BT) * 2, 256, 0, stream>>>(x, Wr, Wn, z);
        topk_kernel<<<TT_TOTAL / 32, 256, 0, stream>>>(z, bias, noise_u,
                                                       out_probs, out_idx);
    } else {
        router_kernel<<<TT_TOTAL / F_TT, 256, 0, stream>>>(
            x, Wr, Wn, bias, noise_u, out_probs, out_idx);
    }
    bias_kernel<<<1, 64, 0, stream>>>(bias, out_bias);
}

// Round 6
// 231.251 us; speedup vs baseline: 1.8393x; 1.3058x over previous
//
#include <hip/hip_runtime.h>
#include <math.h>

#define BB 4
#define SS 4096
#define DD 2048
#define EE 64
#define KK 8
#define TT_TOTAL (BB*SS)      // 16384 tokens
#define E2 128                // stacked outputs (Wr 0..63, Wn 64..127)
#define DK 32                 // D-chunk
#define NC (DD/DK)

typedef double double2_t __attribute__((ext_vector_type(2)));
typedef double double4_t __attribute__((ext_vector_type(4)));

__device__ __forceinline__ double softplus64(double x) {
    return fmax(x, 0.0) + log1p(exp(-fabs(x)));
}

// LDS column swizzle: involution on bits 1..3 keyed by bits 4..6.
// Makes transpose scatter-writes AND pairwise b128 reads conflict-free.
__device__ __forceinline__ int SW(int c) {
    return c ^ (((c >> 4) & 7) << 1);
}

// =====================================================================
// Primary GEMM: block tile 128 tok x 128 out, thread tile 8x8, split-K.
// zp[split][tok][out] partial sums (f64, ascending k within split).
// grid = 128 * KS blocks, 256 threads.
// =====================================================================
#define ROW 130   // LDS row: 128 cols + 2 pad (1040 B, 16B-aligned rows)

template<int KS>
__launch_bounds__(256, 2)
__global__ void gemm8_kernel(const float* __restrict__ x,
                             const float* __restrict__ Wr,
                             const float* __restrict__ Wn,
                             double* __restrict__ zp)
{
    __shared__ __align__(16) double xs[DK][ROW];   // 33280 B : xs[k][SW(tok)]
    __shared__ __align__(16) double ws[DK][ROW];   // 33280 B : ws[k][SW(out)]

    const int tid   = threadIdx.x;
    const int split = blockIdx.x % KS;
    const int bt    = blockIdx.x / KS;
    const int tok0  = bt * 128;
    const int kbase = split * (DD / KS);
    const int NCH   = (DD / KS) / DK;

    // ---- staging mapping: row = tid&127, k-half = tid>>7 ----
    const int stok = tid & 127;
    const int skh  = tid >> 7;            // 0/1 -> k 0..15 / 16..31
    const int scol = SW(stok);
    const float* xsrc = x + (size_t)(tok0 + stok) * DD + kbase + 16 * skh;
    const float* wsrc = ((stok < EE) ? Wr + (size_t)stok * DD
                                     : Wn + (size_t)(stok - EE) * DD)
                        + kbase + 16 * skh;

    // ---- compute mapping: 8 toks {2tg2+e+32h}, 8 outs {2og2+f+32g} ----
    const int og2 = tid & 15;
    const int tg2 = tid >> 4;
    int colx[4], colw[4];
    #pragma unroll
    for (int h = 0; h < 4; ++h) colx[h] = SW(2 * tg2 + 32 * h);
    #pragma unroll
    for (int g = 0; g < 4; ++g) colw[g] = SW(2 * og2 + 32 * g);

    double acc[8][8];
    #pragma unroll
    for (int i = 0; i < 8; ++i)
        #pragma unroll
        for (int j = 0; j < 8; ++j) acc[i][j] = 0.0;

    // preload chunk 0 (16 floats each of x and W)
    float4 xr[4], wr[4];
    #pragma unroll
    for (int i = 0; i < 4; ++i) {
        xr[i] = *reinterpret_cast<const float4*>(xsrc + 4 * i);
        wr[i] = *reinterpret_cast<const float4*>(wsrc + 4 * i);
    }

    for (int c = 0; c < NCH; ++c) {
        __syncthreads();   // previous chunk's reads done

        // transpose-stage to LDS (conflict-free via SW)
        #pragma unroll
        for (int i = 0; i < 4; ++i) {
            const int k = 16 * skh + 4 * i;
            xs[k+0][scol] = (double)xr[i].x;
            xs[k+1][scol] = (double)xr[i].y;
            xs[k+2][scol] = (double)xr[i].z;
            xs[k+3][scol] = (double)xr[i].w;
            ws[k+0][scol] = (double)wr[i].x;
            ws[k+1][scol] = (double)wr[i].y;
            ws[k+2][scol] = (double)wr[i].z;
            ws[k+3][scol] = (double)wr[i].w;
        }
        __syncthreads();

        // prefetch next chunk into registers (lands under compute)
        if (c + 1 < NCH) {
            const int off = (c + 1) * DK;
            #pragma unroll
            for (int i = 0; i < 4; ++i) {
                xr[i] = *reinterpret_cast<const float4*>(xsrc + off + 4 * i);
                wr[i] = *reinterpret_cast<const float4*>(wsrc + off + 4 * i);
            }
        }

        // inner: per k, 8x ds_read_b128 feed 64 f64 FMAs
        #pragma unroll 4
        for (int k = 0; k < DK; ++k) {
            double2_t xv[4], wv[4];
            #pragma unroll
            for (int h = 0; h < 4; ++h)
                xv[h] = *reinterpret_cast<const double2_t*>(&xs[k][colx[h]]);
            #pragma unroll
            for (int g = 0; g < 4; ++g)
                wv[g] = *reinterpret_cast<const double2_t*>(&ws[k][colw[g]]);
            #pragma unroll
            for (int h = 0; h < 4; ++h)
                #pragma unroll
                for (int e = 0; e < 2; ++e)
                    #pragma unroll
                    for (int g = 0; g < 4; ++g) {
                        acc[2*h+e][2*g+0] = fma(xv[h][e], wv[g][0], acc[2*h+e][2*g+0]);
                        acc[2*h+e][2*g+1] = fma(xv[h][e], wv[g][1], acc[2*h+e][2*g+1]);
                    }
        }
    }

    // write partials: zp[split][tok][out]
    double* zbase = zp + (size_t)split * TT_TOTAL * E2;
    #pragma unroll
    for (int h = 0; h < 4; ++h)
        #pragma unroll
        for (int e = 0; e < 2; ++e) {
            const int tok = 2 * tg2 + e + 32 * h;
            double* row = zbase + (size_t)(tok0 + tok) * E2;
            #pragma unroll
            for (int g = 0; g < 4; ++g) {
                double2_t v = {acc[2*h+e][2*g+0], acc[2*h+e][2*g+1]};
                *reinterpret_cast<double2_t*>(&row[2 * og2 + 32 * g]) = v;
            }
        }
}

// =====================================================================
// topk over reduced partials (ascending split order = deterministic)
// =====================================================================
template<int KS>
__launch_bounds__(256, 4)
__global__ void topk2_kernel(const double* __restrict__ zp,
                             const float* __restrict__ bias,
                             const float* __restrict__ noise_u,
                             float* __restrict__ out_probs,
                             float* __restrict__ out_idx)
{
    const int tid  = threadIdx.x;
    const int wid  = tid >> 6;
    const int lane = tid & 63;
    const int tok0 = blockIdx.x * 32;

    for (int tt = 0; tt < 8; ++tt) {
        const int tok = tok0 + wid * 8 + tt;
        const size_t gtok = (size_t)tok;

        double logit = 0.0, noisy = 0.0;
        #pragma unroll
        for (int s = 0; s < KS; ++s) {
            const double* row = zp + (size_t)s * TT_TOTAL * E2 + (size_t)tok * E2;
            logit += row[lane];
            noisy += row[EE + lane];
        }
        const double zv = (double)noise_u[gtok * EE + lane] * softplus64(noisy)
                          + logit + (double)bias[lane];

        double zw = zv;
        bool   sel = false;
        double m0  = 0.0;
        #pragma unroll
        for (int it = 0; it < KK; ++it) {
            double v  = zw;
            int    ix = lane;
            #pragma unroll
            for (int off = 32; off > 0; off >>= 1) {
                const double ov = __shfl_xor(v, off, 64);
                const int    oi = __shfl_xor(ix, off, 64);
                if (ov > v || (ov == v && oi < ix)) { v = ov; ix = oi; }
            }
            if (it == 0) m0 = v;
            if (lane == ix) { sel = true; zw = -INFINITY; }
            if (lane == 0) out_idx[gtok * KK + it] = (float)ix;
        }

        const double ex = sel ? exp(zv - m0) : 0.0;
        double den = ex;
        #pragma unroll
        for (int off = 32; off > 0; off >>= 1) den += __shfl_xor(den, off, 64);

        out_probs[gtok * EE + lane] = (float)(ex / den);
    }
}

// =====================================================================
// Tier-B kernels: verified R5 two-kernel path (16 MiB ws)
// =====================================================================
#define BT 32
#define XT 34
#define WT 66

__launch_bounds__(256, 4)
__global__ void gemm_kernel(const float* __restrict__ x,
                            const float* __restrict__ Wr,
                            const float* __restrict__ Wn,
                            double* __restrict__ zout)
{
    __shared__ __align__(16) double xs[DK][XT];
    __shared__ __align__(16) double ws[DK][WT];

    const int tid  = threadIdx.x;
    const int bt   = blockIdx.x >> 1;
    const int be   = blockIdx.x & 1;
    const int tok0 = bt * BT;
    const int e0   = be * 64;

    const int kk = tid & 31;
    const int tq = tid >> 5;
    const float* xsrc[4];
    const float* wsrc[8];
    #pragma unroll
    for (int j = 0; j < 4; ++j)
        xsrc[j] = x + (size_t)(tok0 + 4 * tq + j) * DD + kk;
    #pragma unroll
    for (int j = 0; j < 4; ++j) {
        const int e  = e0 + 4 * tq + j;
        const int e2 = e0 + 32 + 4 * tq + j;
        wsrc[j]     = ((e  < EE) ? Wr + (size_t)e * DD
                                 : Wn + (size_t)(e  - EE) * DD) + kk;
        wsrc[4 + j] = ((e2 < EE) ? Wr + (size_t)e2 * DD
                                 : Wn + (size_t)(e2 - EE) * DD) + kk;
    }

    const int og = tid & 15;
    const int tp = tid >> 4;

    double acc[2][4];
    #pragma unroll
    for (int t = 0; t < 2; ++t)
        #pragma unroll
        for (int i = 0; i < 4; ++i) acc[t][i] = 0.0;

    float xr[4], wr[8];
    #pragma unroll
    for (int j = 0; j < 4; ++j) xr[j] = xsrc[j][0];
    #pragma unroll
    for (int j = 0; j < 8; ++j) wr[j] = wsrc[j][0];

    for (int c = 0; c < NC; ++c) {
        __syncthreads();
        {
            double4_t xv = {(double)xr[0], (double)xr[1], (double)xr[2], (double)xr[3]};
            *reinterpret_cast<double4_t*>(&xs[kk][4 * tq]) = xv;
            double4_t w0 = {(double)wr[0], (double)wr[1], (double)wr[2], (double)wr[3]};
            *reinterpret_cast<double4_t*>(&ws[kk][4 * tq]) = w0;
            double4_t w1 = {(double)wr[4], (double)wr[5], (double)wr[6], (double)wr[7]};
            *reinterpret_cast<double4_t*>(&ws[kk][32 + 4 * tq]) = w1;
        }
        __syncthreads();
        if (c + 1 < NC) {
            const int off = (c + 1) * DK;
            #pragma unroll
            for (int j = 0; j < 4; ++j) xr[j] = xsrc[j][off];
            #pragma unroll
            for (int j = 0; j < 8; ++j) wr[j] = wsrc[j][off];
        }
        #pragma unroll 4
        for (int k = 0; k < DK; ++k) {
            const double2_t xv = *reinterpret_cast<const double2_t*>(&xs[k][2 * tp]);
            const double2_t w0 = *reinterpret_cast<const double2_t*>(&ws[k][2 * og]);
            const double2_t w1 = *reinterpret_cast<const double2_t*>(&ws[k][32 + 2 * og]);
            acc[0][0] = fma(xv.x, w0.x, acc[0][0]);
            acc[0][1] = fma(xv.x, w0.y, acc[0][1]);
            acc[0][2] = fma(xv.x, w1.x, acc[0][2]);
            acc[0][3] = fma(xv.x, w1.y, acc[0][3]);
            acc[1][0] = fma(xv.y, w0.x, acc[1][0]);
            acc[1][1] = fma(xv.y, w0.y, acc[1][1]);
            acc[1][2] = fma(xv.y, w1.x, acc[1][2]);
            acc[1][3] = fma(xv.y, w1.y, acc[1][3]);
        }
    }

    #pragma unroll
    for (int t = 0; t < 2; ++t) {
        const size_t base = (size_t)(tok0 + 2 * tp + t) * E2 + e0;
        double2_t lo = {acc[t][0], acc[t][1]};
        double2_t hi = {acc[t][2], acc[t][3]};
        *reinterpret_cast<double2_t*>(&zout[base + 2 * og])      = lo;
        *reinterpret_cast<double2_t*>(&zout[base + 32 + 2 * og]) = hi;
    }
}

// =====================================================================
// Tier-C: verified R4 monolithic kernel
// =====================================================================
#define F_XT 34
#define F_WR 130
#define F_ZR 130
#define F_SMEM ((DK*F_XT + DK*F_WR)*8)

__launch_bounds__(256, 3)
__global__ void router_kernel(const float* __restrict__ x,
                              const float* __restrict__ Wr,
                              const float* __restrict__ Wn,
                              const float* __restrict__ bias,
                              const float* __restrict__ noise_u,
                              float* __restrict__ out_probs,
                              float* __restrict__ out_idx)
{
    __shared__ __align__(16) char smem_raw[F_SMEM];
    double (*xs)[F_XT] = reinterpret_cast<double(*)[F_XT]>(smem_raw);
    double (*wt)[F_WR] = reinterpret_cast<double(*)[F_WR]>(smem_raw + DK*F_XT*8);
    double (*zbuf)[F_ZR] = reinterpret_cast<double(*)[F_ZR]>(smem_raw);

    const int tid  = threadIdx.x;
    const int tok0 = blockIdx.x * 32;
    const int stok = tid >> 3;
    const int sfi  = tid & 7;
    const float* xsrc = x + (size_t)(tok0 + stok) * DD + sfi * 4;
    const float* wsrc[4];
    #pragma unroll
    for (int it = 0; it < 4; ++it) {
        const int r = it * 32 + stok;
        wsrc[it] = ((r < EE) ? (Wr + (size_t)r * DD)
                             : (Wn + (size_t)(r - EE) * DD)) + sfi * 4;
    }
    const int tg = tid >> 5;
    const int eg = tid & 31;

    double acc[4][4];
    #pragma unroll
    for (int t = 0; t < 4; ++t)
        #pragma unroll
        for (int i = 0; i < 4; ++i) acc[t][i] = 0.0;

    float4 xr  = *reinterpret_cast<const float4*>(xsrc);
    float4 wr0 = *reinterpret_cast<const float4*>(wsrc[0]);
    float4 wr1 = *reinterpret_cast<const float4*>(wsrc[1]);
    float4 wr2 = *reinterpret_cast<const float4*>(wsrc[2]);
    float4 wr3 = *reinterpret_cast<const float4*>(wsrc[3]);

    for (int c = 0; c < NC; ++c) {
        __syncthreads();
        {
            const int k0 = sfi * 4;
            xs[k0+0][stok] = (double)xr.x;  xs[k0+1][stok] = (double)xr.y;
            xs[k0+2][stok] = (double)xr.z;  xs[k0+3][stok] = (double)xr.w;
            wt[k0+0][stok      ] = (double)wr0.x; wt[k0+1][stok      ] = (double)wr0.y;
            wt[k0+2][stok      ] = (double)wr0.z; wt[k0+3][stok      ] = (double)wr0.w;
            wt[k0+0][stok + 32 ] = (double)wr1.x; wt[k0+1][stok + 32 ] = (double)wr1.y;
            wt[k0+2][stok + 32 ] = (double)wr1.z; wt[k0+3][stok + 32 ] = (double)wr1.w;
            wt[k0+0][stok + 64 ] = (double)wr2.x; wt[k0+1][stok + 64 ] = (double)wr2.y;
            wt[k0+2][stok + 64 ] = (double)wr2.z; wt[k0+3][stok + 64 ] = (double)wr2.w;
            wt[k0+0][stok + 96 ] = (double)wr3.x; wt[k0+1][stok + 96 ] = (double)wr3.y;
            wt[k0+2][stok + 96 ] = (double)wr3.z; wt[k0+3][stok + 96 ] = (double)wr3.w;
        }
        __syncthreads();
        if (c + 1 < NC) {
            const int off = (c + 1) * DK;
            xr  = *reinterpret_cast<const float4*>(xsrc + off);
            wr0 = *reinterpret_cast<const float4*>(wsrc[0] + off);
            wr1 = *reinterpret_cast<const float4*>(wsrc[1] + off);
            wr2 = *reinterpret_cast<const float4*>(wsrc[2] + off);
            wr3 = *reinterpret_cast<const float4*>(wsrc[3] + off);
        }
        #pragma unroll 4
        for (int k = 0; k < DK; ++k) {
            const double2_t xv0 = *reinterpret_cast<const double2_t*>(&xs[k][tg * 4]);
            const double2_t xv1 = *reinterpret_cast<const double2_t*>(&xs[k][tg * 4 + 2]);
            const double2_t w0  = *reinterpret_cast<const double2_t*>(&wt[k][2 * eg]);
            const double2_t w1  = *reinterpret_cast<const double2_t*>(&wt[k][64 + 2 * eg]);
            const double xvv[4] = {xv0.x, xv0.y, xv1.x, xv1.y};
            #pragma unroll
            for (int t = 0; t < 4; ++t) {
                acc[t][0] = fma(xvv[t], w0.x, acc[t][0]);
                acc[t][1] = fma(xvv[t], w0.y, acc[t][1]);
                acc[t][2] = fma(xvv[t], w1.x, acc[t][2]);
                acc[t][3] = fma(xvv[t], w1.y, acc[t][3]);
            }
        }
    }
    __syncthreads();
    #pragma unroll
    for (int t = 0; t < 4; ++t) {
        double2_t lo = {acc[t][0], acc[t][1]};
        double2_t hi = {acc[t][2], acc[t][3]};
        *reinterpret_cast<double2_t*>(&zbuf[tg * 4 + t][2 * eg])      = lo;
        *reinterpret_cast<double2_t*>(&zbuf[tg * 4 + t][64 + 2 * eg]) = hi;
    }
    __syncthreads();

    const int wid  = tid >> 6;
    const int lane = tid & 63;
    for (int tt = 0; tt < 8; ++tt) {
        const int tok = wid * 8 + tt;
        const size_t gtok = (size_t)tok0 + tok;
        const double logit = zbuf[tok][lane];
        const double noisy = zbuf[tok][EE + lane];
        const double zv = (double)noise_u[gtok * EE + lane] * softplus64(noisy)
                          + logit + (double)bias[lane];
        double zw = zv;
        bool   sel = false;
        double m0  = 0.0;
        #pragma unroll
        for (int it = 0; it < KK; ++it) {
            double v  = zw;
            int    ix = lane;
            #pragma unroll
            for (int off = 32; off > 0; off >>= 1) {
                const double ov = __shfl_xor(v, off, 64);
                const int    oi = __shfl_xor(ix, off, 64);
                if (ov > v || (ov == v && oi < ix)) { v = ov; ix = oi; }
            }
            if (it == 0) m0 = v;
            if (lane == ix) { sel = true; zw = -INFINITY; }
            if (lane == 0) out_idx[gtok * KK + it] = (float)ix;
        }
        const double ex = sel ? exp(zv - m0) : 0.0;
        double den = ex;
        #pragma unroll
        for (int off = 32; off > 0; off >>= 1) den += __shfl_xor(den, off, 64);
        out_probs[gtok * EE + lane] = (float)(ex / den);
    }
}

__global__ void bias_kernel(const float* __restrict__ bias,
                            float* __restrict__ out_bias)
{
    const int e = threadIdx.x;
    if (e < EE) {
        const double load_violation = (double)(TT_TOTAL * KK) / EE
                                      - (double)(TT_TOTAL * KK);
        const double s = (load_violation > 0.0) ? 1.0
                         : ((load_violation < 0.0) ? -1.0 : 0.0);
        out_bias[e] = bias[e] + (float)(0.001 * s);
    }
}

extern "C" void kernel_launch(void* const* d_in, const int* in_sizes, int n_in,
                              void* d_out, int out_size, void* d_ws, size_t ws_size,
                              hipStream_t stream)
{
    const float* x       = (const float*)d_in[0];
    const float* Wr      = (const float*)d_in[1];
    const float* Wn      = (const float*)d_in[2];
    const float* bias    = (const float*)d_in[3];
    const float* noise_u = (const float*)d_in[4];

    float* out       = (float*)d_out;
    float* out_probs = out;
    float* out_idx   = out + (size_t)TT_TOTAL * EE;
    float* out_bias  = out + (size_t)TT_TOTAL * EE + (size_t)TT_TOTAL * KK;

    const size_t z1 = (size_t)TT_TOTAL * E2 * sizeof(double);   // 16 MiB

    if (ws_size >= 4 * z1) {
        double* zp = (double*)d_ws;
        gemm8_kernel<4><<<128 * 4, 256, 0, stream>>>(x, Wr, Wn, zp);
        topk2_kernel<4><<<TT_TOTAL / 32, 256, 0, stream>>>(zp, bias, noise_u,
                                                           out_probs, out_idx);
    } else if (ws_size >= 2 * z1) {
        double* zp = (double*)d_ws;
        gemm8_kernel<2><<<128 * 2, 256, 0, stream>>>(x, Wr, Wn, zp);
        topk2_kernel<2><<<TT_TOTAL / 32, 256, 0, stream>>>(zp, bias, noise_u,
                                                           out_probs, out_idx);
    } else if (ws_size >= z1) {
        double* z = (double*)d_ws;
        gemm_kernel<<<(TT_TOTAL / BT) * 2, 256, 0, stream>>>(x, Wr, Wn, z);
        topk2_kernel<1><<<TT_TOTAL / 32, 256, 0, stream>>>(z, bias, noise_u,
                                                           out_probs, out_idx);
    } else {
        router_kernel<<<TT_TOTAL / 32, 256, 0, stream>>>(
            x, Wr, Wn, bias, noise_u, out_probs, out_idx);
    }
    bias_kernel<<<1, 64, 0, stream>>>(bias, out_bias);
}